// Round 1
// baseline (214.026 us; speedup 1.0000x reference)
//
#include <hip/hip_runtime.h>

#define NN 100000
#define NE 1250000
#define D 64

// ---------------------------------------------------------------------------
// Kernel 1: edge aggregation. dst is sorted, so each wave takes 64 consecutive
// edges, lane = feature. Run-length accumulate in a register while dst is
// unchanged; flush with f32 hardware atomics on segment change. Edge src/dst
// are preloaded lane-parallel and broadcast via __shfl. x-row loads are
// software-pipelined 8-deep for memory-level parallelism.
// ---------------------------------------------------------------------------
__global__ __launch_bounds__(256) void k_agg(const float* __restrict__ x,
                                             const int* __restrict__ src,
                                             const int* __restrict__ dst,
                                             float* __restrict__ agg,
                                             float* __restrict__ deg) {
    const int lane = threadIdx.x & 63;
    const int wave = blockIdx.x * (blockDim.x >> 6) + (threadIdx.x >> 6);
    const long base = (long)wave * 64;
    if (base >= NE) return;

    const int count = (int)min((long)64, (long)NE - base);

    // lane-parallel preload of this wave's edge list
    int sv = 0, dv = -1;
    if (base + lane < NE) {
        sv = src[base + lane];
        dv = dst[base + lane];
    }

    float acc = 0.0f;
    int cnt = 0;
    int cur = __shfl(dv, 0);

    for (int i0 = 0; i0 < count; i0 += 8) {
        const int m = min(8, count - i0);
        float xr[8];
        int dd[8];
        // issue up to 8 gather loads back-to-back (MLP)
        #pragma unroll
        for (int j = 0; j < 8; ++j) {
            if (j < m) {
                int s = __shfl(sv, i0 + j);
                dd[j] = __shfl(dv, i0 + j);
                xr[j] = x[(long)s * D + lane];
            }
        }
        // consume: run-length accumulate, flush on dst change
        #pragma unroll
        for (int j = 0; j < 8; ++j) {
            if (j < m) {
                if (dd[j] != cur) {
                    unsafeAtomicAdd(&agg[(long)cur * D + lane], acc);
                    if (lane == 0) unsafeAtomicAdd(&deg[cur], (float)cnt);
                    acc = 0.0f;
                    cnt = 0;
                    cur = dd[j];
                }
                acc += xr[j];
                cnt++;
            }
        }
    }
    if (cnt > 0) {
        unsafeAtomicAdd(&agg[(long)cur * D + lane], acc);
        if (lane == 0) unsafeAtomicAdd(&deg[cur], (float)cnt);
    }
}

// ---------------------------------------------------------------------------
// Kernel 2: out[n][j] = b[j] + sum_k x[n][k]*Ws[k][j] + h[n][k]*Wn[k][j]
// with h[n][k] = agg[n][k] / max(deg[n],1).
// W_self/W_neigh staged once per block in LDS (32 KB -> 4 blocks/CU).
// One wave per node: lane = output column j. x/h rows staged wave-locally in
// LDS and consumed as float4 broadcast reads (conflict-free); W row reads are
// lane-consecutive (2-way bank aliasing = free on CDNA4).
// ---------------------------------------------------------------------------
__global__ __launch_bounds__(256) void k_out(const float* __restrict__ x,
                                             const float* __restrict__ Wself,
                                             const float* __restrict__ Wneigh,
                                             const float* __restrict__ b,
                                             const float* __restrict__ agg,
                                             const float* __restrict__ deg,
                                             float* __restrict__ out) {
    __shared__ float Ws[D * D];
    __shared__ float Wn[D * D];
    __shared__ float bs[D];
    __shared__ float xs[4][D];
    __shared__ float hs[4][D];

    const int tid = threadIdx.x;
    // cooperative staging of both weight matrices (float4)
    for (int i = tid; i < D * D / 4; i += 256) {
        ((float4*)Ws)[i] = ((const float4*)Wself)[i];
        ((float4*)Wn)[i] = ((const float4*)Wneigh)[i];
    }
    if (tid < D) bs[tid] = b[tid];
    __syncthreads();

    const int w = tid >> 6;
    const int lane = tid & 63;
    const int stride = gridDim.x * 4;

    for (int n0 = blockIdx.x * 4; n0 < NN; n0 += stride) {
        const int n = n0 + w;
        if (n < NN) {
            const float xv = x[(long)n * D + lane];
            const float av = agg[(long)n * D + lane];
            const float dg = deg[n];
            const float inv = (dg > 0.5f) ? (1.0f / dg) : 0.0f;
            xs[w][lane] = xv;
            hs[w][lane] = av * inv;
            // wave-local LDS RAW: no barrier needed (same wave)
            float acc = bs[lane];
            #pragma unroll
            for (int k4 = 0; k4 < D / 4; ++k4) {
                const float4 xk = ((const float4*)&xs[w][0])[k4];
                const float4 hk = ((const float4*)&hs[w][0])[k4];
                const int k = k4 * 4;
                acc += xk.x * Ws[(k + 0) * D + lane] + hk.x * Wn[(k + 0) * D + lane];
                acc += xk.y * Ws[(k + 1) * D + lane] + hk.y * Wn[(k + 1) * D + lane];
                acc += xk.z * Ws[(k + 2) * D + lane] + hk.z * Wn[(k + 2) * D + lane];
                acc += xk.w * Ws[(k + 3) * D + lane] + hk.w * Wn[(k + 3) * D + lane];
            }
            out[(long)n * D + lane] = acc;
        }
    }
}

extern "C" void kernel_launch(void* const* d_in, const int* in_sizes, int n_in,
                              void* d_out, int out_size, void* d_ws, size_t ws_size,
                              hipStream_t stream) {
    const float* x      = (const float*)d_in[0];
    const float* Wself  = (const float*)d_in[1];
    const float* Wneigh = (const float*)d_in[2];
    const float* b      = (const float*)d_in[3];
    const int*   src    = (const int*)d_in[4];
    const int*   dst    = (const int*)d_in[5];
    float* out = (float*)d_out;

    float* agg = (float*)d_ws;                     // [NN * D]
    float* deg = agg + (size_t)NN * D;             // [NN]

    // d_ws is re-poisoned to 0xAA before every launch: zero our scratch
    hipMemsetAsync(d_ws, 0, ((size_t)NN * D + NN) * sizeof(float), stream);

    const int waves1 = (NE + 63) / 64;
    const int blocks1 = (waves1 + 3) / 4;
    k_agg<<<blocks1, 256, 0, stream>>>(x, src, dst, agg, deg);

    // 4 blocks/CU (34 KB LDS each) * 256 CU = 1024 resident blocks
    k_out<<<1024, 256, 0, stream>>>(x, Wself, Wneigh, b, agg, deg, out);
}

// Round 2
// 182.463 us; speedup vs baseline: 1.1730x; 1.1730x over previous
//
#include <hip/hip_runtime.h>

#define NN 100000
#define NE 1250000
#define D 64

// ---------------------------------------------------------------------------
// k_rowptr: dst is sorted ascending. row_ptr[v] = first edge index with
// dst >= v; row_ptr[NN] = NE. Every entry written exactly once per call
// (no memset needed; d_ws is re-poisoned before every launch).
// ---------------------------------------------------------------------------
__global__ __launch_bounds__(256) void k_rowptr(const int* __restrict__ dst,
                                                int* __restrict__ row_ptr) {
    const int i = blockIdx.x * 256 + threadIdx.x;
    if (i >= NE) return;
    const int d = dst[i];
    const int prev = (i == 0) ? -1 : dst[i - 1];
    for (int v = prev + 1; v <= d; ++v) row_ptr[v] = i;
    if (i == NE - 1) {
        for (int v = d + 1; v <= NN; ++v) row_ptr[v] = NE;
    }
}

// ---------------------------------------------------------------------------
// k_neigh: CSR mean aggregation. One wave per node, lane = feature.
// Edge loads within a node are independent -> 8-deep MLP batches.
// src[e] is wave-uniform -> scalar loads. Writes normalized h directly:
// no atomics, no deg array, no zero-init pass.
// ---------------------------------------------------------------------------
__global__ __launch_bounds__(256) void k_neigh(const float* __restrict__ x,
                                               const int* __restrict__ src,
                                               const int* __restrict__ row_ptr,
                                               float* __restrict__ h) {
    const int lane = threadIdx.x & 63;
    const int w = __builtin_amdgcn_readfirstlane(threadIdx.x >> 6);
    const int v = blockIdx.x * 4 + w;
    if (v >= NN) return;
    const int lo = row_ptr[v];
    const int hi = row_ptr[v + 1];

    float acc = 0.0f;
    for (int e = lo; e < hi; e += 8) {
        const int m = hi - e;  // wave-uniform
        float r[8];
        #pragma unroll
        for (int j = 0; j < 8; ++j) {
            if (j < m) r[j] = x[(size_t)src[e + j] * D + lane];
        }
        #pragma unroll
        for (int j = 0; j < 8; ++j) {
            if (j < m) acc += r[j];
        }
    }
    const float inv = (hi > lo) ? 1.0f / (float)(hi - lo) : 0.0f;
    h[(size_t)v * D + lane] = acc * inv;
}

// ---------------------------------------------------------------------------
// k_out: out[n][j] = b[j] + sum_k x[n][k]*Ws[k][j] + h[n][k]*Wn[k][j].
// Lane j owns W columns in VGPRs (128 regs, loaded once per wave, amortized
// over ~33 nodes via grid-stride). Node row values are wave-uniform ->
// scalar loads (constant cache), consumed as the SGPR operand of v_fma_f32.
// Zero LDS: the round-1 kernel was LDS-issue-bound at 40% VALUBusy.
// ---------------------------------------------------------------------------
__global__ __launch_bounds__(256, 3) void k_out(const float* __restrict__ x,
                                                const float* __restrict__ h,
                                                const float* __restrict__ Wself,
                                                const float* __restrict__ Wneigh,
                                                const float* __restrict__ b,
                                                float* __restrict__ out) {
    const int lane = threadIdx.x & 63;
    const int w = __builtin_amdgcn_readfirstlane(threadIdx.x >> 6);
    const int wave0 = blockIdx.x * 4 + w;
    const int nwaves = gridDim.x * 4;

    // Per-wave weight staging: lane j holds column j of both matrices.
    float ws[D], wn[D];
    #pragma unroll
    for (int k = 0; k < D; ++k) {
        ws[k] = Wself[k * D + lane];
        wn[k] = Wneigh[k * D + lane];
    }
    const float bv = b[lane];

    for (int n = wave0; n < NN; n += nwaves) {
        const int nu = __builtin_amdgcn_readfirstlane(n);
        const float* __restrict__ xr = x + (size_t)nu * D;
        const float* __restrict__ hr = h + (size_t)nu * D;
        float acc = bv;
        #pragma unroll
        for (int k = 0; k < D; ++k) {
            acc = fmaf(xr[k], ws[k], acc);   // s_load operand + VGPR weight
            acc = fmaf(hr[k], wn[k], acc);
        }
        out[(size_t)nu * D + lane] = acc;
    }
}

extern "C" void kernel_launch(void* const* d_in, const int* in_sizes, int n_in,
                              void* d_out, int out_size, void* d_ws, size_t ws_size,
                              hipStream_t stream) {
    const float* x      = (const float*)d_in[0];
    const float* Wself  = (const float*)d_in[1];
    const float* Wneigh = (const float*)d_in[2];
    const float* b      = (const float*)d_in[3];
    const int*   src    = (const int*)d_in[4];
    const int*   dst    = (const int*)d_in[5];
    float* out = (float*)d_out;

    float* h       = (float*)d_ws;                       // [NN * D]
    int*   row_ptr = (int*)(h + (size_t)NN * D);         // [NN + 1]

    k_rowptr<<<(NE + 255) / 256, 256, 0, stream>>>(dst, row_ptr);
    k_neigh<<<(NN + 3) / 4, 256, 0, stream>>>(x, src, row_ptr, h);
    // 768 blocks = 3 blocks/CU * 256 CU (launch_bounds(256,3)), 3072 waves
    k_out<<<768, 256, 0, stream>>>(x, h, Wself, Wneigh, b, out);
}